// Round 1
// baseline (27.691 us; speedup 1.0000x reference)
//
#include <hip/hip_runtime.h>

// NuFACoef: out[b] = sum_{i,j} coef[i][j] * trace_ij / 16^(i+j+2)
// where trace_ij = sum_k colsum(x^(i+2))[k]^(j+1).
// colsum(x^m) = ones^T x^m, computed iteratively: u1 = ones^T x, u_{m+1} = u_m @ x.
// One wave per batch; x held entirely in registers (lane = 16 rows x 4 cols).

__device__ __forceinline__ float4 xor_reduce_rows(float4 v) {
    v.x += __shfl_xor(v.x, 16, 64); v.y += __shfl_xor(v.y, 16, 64);
    v.z += __shfl_xor(v.z, 16, 64); v.w += __shfl_xor(v.w, 16, 64);
    v.x += __shfl_xor(v.x, 32, 64); v.y += __shfl_xor(v.y, 32, 64);
    v.z += __shfl_xor(v.z, 32, 64); v.w += __shfl_xor(v.w, 32, 64);
    return v;
}

__global__ __launch_bounds__(256) void nufa_kernel(
    const float* __restrict__ x, const float* __restrict__ coef,
    float* __restrict__ out, int B)
{
    const int wave = threadIdx.x >> 6;   // 0..3, one batch per wave
    const int lane = threadIdx.x & 63;
    const int b = blockIdx.x * 4 + wave;
    if (b >= B) return;

    const int rg = lane >> 4;   // row group: rows 16*rg .. 16*rg+15
    const int cg = lane & 15;   // col group: cols 4*cg .. 4*cg+3

    // x is [64][64] row-major per batch = 1024 float4; f4 idx = row*16 + col/4.
    // Lane t holds f4[256*rg + 16*k + cg], k = 0..15  (16 rows x 4 cols block).
    // Per k the wave reads 4 contiguous 256B segments -> coalesced.
    const float4* x4 = reinterpret_cast<const float4*>(x)
                       + (size_t)b * 1024 + 256 * rg + cg;
    float4 xr[16];
    #pragma unroll
    for (int k = 0; k < 16; ++k) xr[k] = x4[16 * k];

    // Scaled coefficients: cs[i][j] = coef[i][j] / 16^(i+j+2) (exact pow2 scales).
    float cs[4][4];
    #pragma unroll
    for (int i = 0; i < 4; ++i) {
        #pragma unroll
        for (int j = 0; j < 4; ++j) {
            const float inv = 1.0f / (float)(1ull << (4 * (i + j + 2)));
            cs[i][j] = coef[i * 4 + j] * inv;
        }
    }

    // u1 = colsum(x): partial over this lane's 16 rows, then reduce row groups.
    float4 u = {0.f, 0.f, 0.f, 0.f};
    #pragma unroll
    for (int k = 0; k < 16; ++k) {
        u.x += xr[k].x; u.y += xr[k].y; u.z += xr[k].z; u.w += xr[k].w;
    }
    u = xor_reduce_rows(u);   // every lane now has colsums for its 4 columns

    float contrib = 0.f;
    #pragma unroll
    for (int m = 0; m < 4; ++m) {
        // u_new[c] = sum_i u[i] * x[i][c]; lane covers i in [16*rg, 16*rg+16).
        // u[i] lives as component (i&3) on lane (i>>2) (any row group).
        float4 acc = {0.f, 0.f, 0.f, 0.f};
        #pragma unroll
        for (int k = 0; k < 16; ++k) {
            const int src = 4 * rg + (k >> 2);      // per-lane source lane
            const float uk = ((k & 3) == 0) ? __shfl(u.x, src, 64)
                           : ((k & 3) == 1) ? __shfl(u.y, src, 64)
                           : ((k & 3) == 2) ? __shfl(u.z, src, 64)
                           :                  __shfl(u.w, src, 64);
            acc.x += uk * xr[k].x; acc.y += uk * xr[k].y;
            acc.z += uk * xr[k].z; acc.w += uk * xr[k].w;
        }
        u = xor_reduce_rows(acc);   // u = colsum(x^(m+2)), duplicated across rgs

        // trace terms: sum over this lane's 4 columns of cs[m][j] * u^(j+1)
        #pragma unroll
        for (int c = 0; c < 4; ++c) {
            const float v1 = (c == 0) ? u.x : (c == 1) ? u.y : (c == 2) ? u.z : u.w;
            const float v2 = v1 * v1;
            const float v3 = v2 * v1;
            const float v4 = v2 * v2;
            contrib += cs[m][0] * v1 + cs[m][1] * v2 + cs[m][2] * v3 + cs[m][3] * v4;
        }
    }

    // Full-wave reduce. Each column's contribution appears once per row group
    // (4x duplication) -> scale by 1/4.
    #pragma unroll
    for (int d = 1; d < 64; d <<= 1) contrib += __shfl_xor(contrib, d, 64);
    if (lane == 0) out[b] = contrib * 0.25f;
}

extern "C" void kernel_launch(void* const* d_in, const int* in_sizes, int n_in,
                              void* d_out, int out_size, void* d_ws, size_t ws_size,
                              hipStream_t stream) {
    const float* x    = (const float*)d_in[0];
    const float* coef = (const float*)d_in[1];
    float* out        = (float*)d_out;
    const int B = in_sizes[0] / 4096;          // 64*64 elements per batch
    const int blocks = (B + 3) / 4;            // 4 batches (waves) per block
    nufa_kernel<<<blocks, 256, 0, stream>>>(x, coef, out, B);
}